// Round 8
// baseline (486.959 us; speedup 1.0000x reference)
//
#include <hip/hip_runtime.h>
#include <hip/hip_fp16.h>
#include <cstdint>
#include <cstddef>

#define B_ 2
#define C_ 64
#define H_ 256
#define W_ 256
#define HW_ (H_*W_)
#define DG_ 8
#define CG_ 8
#define KK_ 9
#define NOFF_ 144
#define NMSK_ 72
#define NTOT_ 216
#define KRED_ 1152   // 128 * 9
#define XPH_ 258     // padded spatial dim (H+2)

typedef __bf16 bf16x8 __attribute__((ext_vector_type(8)));
typedef _Float16 half8 __attribute__((ext_vector_type(8)));
typedef short  short8 __attribute__((ext_vector_type(8)));
typedef float  f32x4  __attribute__((ext_vector_type(4)));

__device__ __forceinline__ short f2bf(float f) {
    union { float f; uint32_t u; } a; a.f = f;
    uint32_t u = a.u;
    uint32_t r = (u + 0x7fffu + ((u >> 16) & 1u)) >> 16;
    return (short)r;
}

// async global->LDS, 16B per lane: dest = wave-uniform base + lane*16
typedef __attribute__((address_space(1))) const unsigned int g_u32;
typedef __attribute__((address_space(3))) unsigned int l_u32;
__device__ __forceinline__ void gl_lds16(const void* g, void* l) {
    __builtin_amdgcn_global_load_lds((g_u32*)g, (l_u32*)l, 16, 0, 0);
}

// ---------------- prep: pack (vectorized) + both weight transposes --------------
// blocks [0,516): pack one (b,row): 256 thr = 4 c4 x 64 pixel-quads, float4 loads
// blocks [516,1668): conv weights -> bf16 step-major slot-swizzled Bw
// blocks [1668,1812): apply weights -> f16 chunk-major Bw3
__global__ __launch_bounds__(256) void prep_all(
    const float* __restrict__ ref, const float* __restrict__ nbr,
    const float* __restrict__ off_w, const float* __restrict__ msk_w,
    const float* __restrict__ weight,
    short* __restrict__ xp, short* __restrict__ nbf,
    short* __restrict__ Bw, short* __restrict__ Bw3)
{
    const int bid = blockIdx.x;
    const int tid = threadIdx.x;

    if (bid < 516) {
        const int b  = bid / XPH_;
        const int yi = bid - b * XPH_;
        const int yg = yi - 1;
        const bool rowv = ((unsigned)yg < H_);
        const int c4 = tid >> 6;          // 0..3
        const int qd = tid & 63;          // pixel quad
        const float* base = (c4 < 2 ? ref : nbr)
                            + ((size_t)b * 64 + (c4 & 1) * 32) * HW_
                            + (size_t)(rowv ? yg : 0) * W_;
        short* rowbase = xp + (((size_t)(b * 4 + c4) * XPH_ + yi) * XPH_) * 32;

        auto packPix = [&](int xi) {
            const int xg = xi - 1;
            const bool valid = rowv && ((unsigned)xg < W_);
            short* dst = rowbase + (size_t)xi * 32;
            const int sig = (xi >> 1) & 3;
            #pragma unroll
            for (int q = 0; q < 4; ++q) {
                float v[8];
                if (valid) {
                    #pragma unroll
                    for (int j = 0; j < 8; ++j) v[j] = base[(size_t)(q*8+j) * HW_ + xg];
                } else {
                    #pragma unroll
                    for (int j = 0; j < 8; ++j) v[j] = 0.f;
                }
                short8 o;
                #pragma unroll
                for (int j = 0; j < 8; ++j) o[j] = f2bf(v[j]);
                *reinterpret_cast<short8*>(dst + ((q ^ sig) * 8)) = o;
                if (c4 >= 2 && valid) {
                    union { half8 h8; short8 s8; } u;
                    #pragma unroll
                    for (int j = 0; j < 8; ++j) u.h8[j] = (_Float16)v[j];
                    *reinterpret_cast<short8*>(
                        nbf + ((size_t)(b * 8 + (c4 - 2) * 4 + q) * HW_
                               + (size_t)yg * W_ + xg) * 8) = u.s8;
                }
            }
        };

        if (rowv && qd < 63) {
            // fast path: 4 interior pixels xi = 4*qd+1 .. 4*qd+4, aligned float4 loads
            const int xg0 = qd * 4;       // 0..248, 16B-aligned in row
            #pragma unroll
            for (int q = 0; q < 4; ++q) {
                f32x4 vj[8];
                #pragma unroll
                for (int j = 0; j < 8; ++j)
                    vj[j] = *reinterpret_cast<const f32x4*>(base + (size_t)(q*8+j) * HW_ + xg0);
                #pragma unroll
                for (int k = 0; k < 4; ++k) {
                    const int xi = xg0 + 1 + k;
                    const int sig = (xi >> 1) & 3;
                    short8 o;
                    #pragma unroll
                    for (int j = 0; j < 8; ++j) o[j] = f2bf(vj[j][k]);
                    *reinterpret_cast<short8*>(rowbase + (size_t)xi * 32 + ((q ^ sig) * 8)) = o;
                    if (c4 >= 2) {
                        union { half8 h8; short8 s8; } u;
                        #pragma unroll
                        for (int j = 0; j < 8; ++j) u.h8[j] = (_Float16)vj[j][k];
                        *reinterpret_cast<short8*>(
                            nbf + ((size_t)(b * 8 + (c4 - 2) * 4 + q) * HW_
                                   + (size_t)yg * W_ + (xi - 1)) * 8) = u.s8;
                    }
                }
            }
        } else if (qd < 63) {
            // invalid row: zero the 4 pixels
            packPix(qd * 4 + 1); packPix(qd * 4 + 2);
            packPix(qd * 4 + 3); packPix(qd * 4 + 4);
        } else {
            // qd == 63: edge pixels {0, 253, 254, 255, 256, 257}
            packPix(0);
            packPix(253); packPix(254); packPix(255);
            packPix(256); packPix(257);
        }
    } else if (bid < 1668) {
        // ---- conv weights: Bw[s][n][slot][8ch], s = c4*9 + tap ----
        int idx = (bid - 516) * 256 + tid;   // 36*256*32 = 294912
        int s    = idx >> 13;
        int rem  = idx & 8191;
        int n    = rem >> 5;
        int slot = (rem >> 3) & 3;
        int j    = rem & 7;
        int q    = slot ^ ((n >> 1) & 3);
        int c4   = s / 9;
        int tap  = s - c4 * 9;
        int ch   = c4 * 32 + q * 8 + j;
        float v = 0.f;
        if (n < NOFF_)      v = off_w[(size_t)n * KRED_ + ch * 9 + tap];
        else if (n < NTOT_) v = msk_w[(size_t)(n - NOFF_) * KRED_ + ch * 9 + tap];
        Bw[idx] = f2bf(v);
    } else {
        // ---- apply weights: Bw3[18][64][slot4][8] f16 ----
        int idx = (bid - 1668) * 256 + tid;   // 18*2048 = 36864
        int kc   = idx >> 11;
        int rem  = idx & 2047;
        int n    = rem >> 5;
        int slot = (rem >> 3) & 3;
        int j    = rem & 7;
        int q    = slot ^ ((n >> 1) & 3);
        int k    = kc >> 1;
        int g    = ((kc & 1) << 2) + q;
        int ci   = g * 8 + j;
        union { _Float16 h; short s; } cv;
        cv.h = (_Float16)weight[((size_t)n * 64 + ci) * 9 + k];
        Bw3[idx] = cv.s;
    }
}

// ---------------- fused kernel: conv phase -> LDS offmsk -> apply phase ---------
struct OffV { float dy, dx, mm; };
struct GathV { half8 c00, c01, c10, c11; float a00, a01, a10, a11; };

__global__ __launch_bounds__(512, 4) void fused_conv_apply(
    const short* __restrict__ xp, const short* __restrict__ Bw,
    const float* __restrict__ off_b, const float* __restrict__ msk_b,
    const short* __restrict__ nbf, const short* __restrict__ Bw3,
    const float* __restrict__ bias, float* __restrict__ out)
{
    __shared__ __align__(16) short AsBuf[2][4608];        // conv 9KB/buf; apply reuses 8KB
    __shared__ __align__(16) short offmsk[NTOT_ * 128];   // 55296 B

    const int tid  = threadIdx.x;
    const int lane = tid & 63;
    const int wid  = tid >> 6;          // 0..7
    const int wm   = wid & 1;           // px half (64)
    const int wn   = wid >> 1;          // n quarter (64)
    const int col     = lane & 15;
    const int quad    = lane >> 4;
    const int rowbase = quad * 4;

    // XCD-aware bijective swizzle (1024 blocks % 8 == 0)
    const int bid = blockIdx.x;
    const int wg  = (bid & 7) * 128 + (bid >> 3);
    const int m0 = wg << 7;
    const int b  = m0 >> 16;
    const int h  = (m0 >> 8) & 255;
    const int w0 = m0 & 255;

    // ============================ conv phase ====================================
    {
        int bOff[4];
        #pragma unroll
        for (int nt = 0; nt < 4; ++nt) {
            int n = wn * 64 + nt * 16 + col;
            bOff[nt] = (n * 4 + (quad ^ ((n >> 1) & 3))) * 8;
        }
        int pxv[4];
        #pragma unroll
        for (int mt = 0; mt < 4; ++mt) pxv[mt] = wm * 64 + mt * 16 + col;

        f32x4 acc[4][4];
        #pragma unroll
        for (int i = 0; i < 4; ++i)
            #pragma unroll
            for (int j = 0; j < 4; ++j) acc[i][j] = f32x4{0.f, 0.f, 0.f, 0.f};

        auto stageA = [&](int win, int bb) {
            const int c4s = win / 3;
            const int dys = win - c4s * 3;
            const short* sA = xp + (((size_t)(b * 4 + c4s) * XPH_ + (h + dys)) * XPH_
                                    + w0) * 32;
            char* dA = (char*)&AsBuf[bb][0];
            gl_lds16(sA + (size_t)tid * 8, dA + wid * 1024);
            if (tid < 32) gl_lds16(sA + (size_t)(512 + tid) * 8, dA + 8192);
        };

        // 2-deep B register pipeline
        bf16x8 bvC[4];
        #pragma unroll
        for (int nt = 0; nt < 4; ++nt)
            bvC[nt] = *reinterpret_cast<const bf16x8*>(Bw + bOff[nt]);

        stageA(0, 0);
        __syncthreads();

        #pragma unroll 1
        for (int win = 0; win < 12; ++win) {
            const int bb = win & 1;
            if (win < 11) stageA(win + 1, bb ^ 1);
            const short* AsC = &AsBuf[bb][0];

            #pragma unroll
            for (int dx = 0; dx < 3; ++dx) {
                const int s = win * 3 + dx;

                bf16x8 bvN[4];
                if (s < 35) {
                    const short* bp = Bw + ((size_t)(s + 1) << 13);
                    #pragma unroll
                    for (int nt = 0; nt < 4; ++nt)
                        bvN[nt] = *reinterpret_cast<const bf16x8*>(bp + bOff[nt]);
                }

                bf16x8 af[4];
                #pragma unroll
                for (int mt = 0; mt < 4; ++mt) {
                    const int px = pxv[mt] + dx;
                    af[mt] = *reinterpret_cast<const bf16x8*>(
                        &AsC[(px * 4 + (quad ^ ((px >> 1) & 3))) * 8]);
                }

                __builtin_amdgcn_s_setprio(1);
                #pragma unroll
                for (int mt = 0; mt < 4; ++mt)
                    #pragma unroll
                    for (int nt = 0; nt < 4; ++nt)
                        acc[mt][nt] = __builtin_amdgcn_mfma_f32_16x16x32_bf16(
                            af[mt], bvC[nt], acc[mt][nt], 0, 0, 0);
                __builtin_amdgcn_s_setprio(0);

                if (s < 35) {
                    #pragma unroll
                    for (int nt = 0; nt < 4; ++nt) bvC[nt] = bvN[nt];
                }
            }
            __syncthreads();
        }

        // epilogue: bias (+sigmoid for mask rows) -> LDS offmsk, XOR-swizzled
        #pragma unroll
        for (int mt = 0; mt < 4; ++mt) {
            const int p4 = wm * 64 + mt * 16 + rowbase;
            #pragma unroll
            for (int nt = 0; nt < 4; ++nt) {
                const int n = wn * 64 + nt * 16 + col;
                if (n >= NTOT_) continue;
                const bool is_off = (n < NOFF_);
                const float bia = is_off ? off_b[n] : msk_b[n - NOFF_];
                union { uint2 u; __half hx[4]; } pk;
                #pragma unroll
                for (int rr = 0; rr < 4; ++rr) {
                    float v = acc[mt][nt][rr] + bia;
                    if (!is_off) v = 1.f / (1.f + __expf(-v));
                    pk.hx[rr] = __float2half(v);
                }
                const int byt = n * 256 + ((2 * p4) ^ ((n & 7) << 4));
                *(uint2*)((char*)offmsk + byt) = pk.u;
            }
        }
    }
    __syncthreads();   // offmsk visible; conv As reads all complete

    // ============================ apply phase ===================================
    {
        const int p     = tid & 127;        // pixel within tile
        const int q     = tid >> 7;         // 0..3: group-slot within chunk
        const int w     = w0 + p;
        const int slotW = q ^ ((p >> 1) & 3);

        auto ldsOff = [&](int n, int pp) -> float {
            const int byt = n * 256 + ((2 * pp) ^ ((n & 7) << 4));
            return __half2float(*reinterpret_cast<const __half*>(
                (const char*)offmsk + byt));
        };
        auto loadOffs = [&](int kc) -> OffV {
            const int k = kc >> 1;
            const int g = ((kc & 1) << 2) + q;
            OffV o;
            o.dy = ldsOff(g * 18 + 2 * k,     p);
            o.dx = ldsOff(g * 18 + 2 * k + 1, p);
            o.mm = ldsOff(NOFF_ + g * 9 + k,  p);
            return o;
        };

        auto issueGather = [&](int kc, OffV o) -> GathV {
            const int k  = kc >> 1;
            const int g  = ((kc & 1) << 2) + q;
            const int ky = k / 3;
            const int kx = k - ky * 3;
            float ys = (float)(h - 1 + ky) + o.dy;
            float xs = (float)(w - 1 + kx) + o.dx;
            float y0f = floorf(ys), x0f = floorf(xs);
            float wy = ys - y0f, wx = xs - x0f;
            int y0 = (int)y0f, x0 = (int)x0f;
            int y1 = y0 + 1, x1 = x0 + 1;
            int yc0 = min(max(y0, 0), H_-1), yc1 = min(max(y1, 0), H_-1);
            float wy0v = (1.f - wy) * (((unsigned)y0 < H_) ? o.mm : 0.f);
            float wy1v = wy * (((unsigned)y1 < H_) ? o.mm : 0.f);
            int xb = min(max(x0, 0), W_-2);
            float wx0v = (((unsigned)x0 < W_) ? (1.f - wx) : 0.f);
            float wx1v = (((unsigned)x1 < W_) ? wx : 0.f);
            float sx0 = (x0 == xb) ? wx0v : ((x1 == xb) ? wx1v : 0.f);
            float sx1 = (x1 == xb + 1) ? wx1v : ((x0 == xb + 1) ? wx0v : 0.f);
            GathV gv;
            gv.a00 = wy0v * sx0; gv.a01 = wy0v * sx1;
            gv.a10 = wy1v * sx0; gv.a11 = wy1v * sx1;
            const short* nb = nbf + (size_t)(b * 8 + g) * HW_ * 8;
            const short* r0 = nb + ((size_t)yc0 * W_ + xb) * 8;
            const short* r1 = nb + ((size_t)yc1 * W_ + xb) * 8;
            gv.c00 = *reinterpret_cast<const half8*>(r0);
            gv.c01 = *reinterpret_cast<const half8*>(r0 + 8);
            gv.c10 = *reinterpret_cast<const half8*>(r1);
            gv.c11 = *reinterpret_cast<const half8*>(r1 + 8);
            return gv;
        };

        auto combineWrite = [&](int kc, const GathV& gv) {
            union { half8 h8; short8 s8; } u;
            #pragma unroll
            for (int c = 0; c < CG_; ++c) {
                float v = gv.a00 * (float)gv.c00[c] + gv.a01 * (float)gv.c01[c]
                        + gv.a10 * (float)gv.c10[c] + gv.a11 * (float)gv.c11[c];
                u.h8[c] = (_Float16)v;
            }
            *reinterpret_cast<short8*>(&AsBuf[kc & 1][(p * 4 + slotW) * 8]) = u.s8;
        };

        // per-thread B fragment address (contiguous 1 KB per wave, L1/L2-hot)
        const int nB = wn * 16 + col;
        const short* bPtr = Bw3 + ((nB * 4 + (quad ^ ((nB >> 1) & 3))) << 3);

        f32x4 acc2[4];
        #pragma unroll
        for (int mt = 0; mt < 4; ++mt) acc2[mt] = f32x4{0.f, 0.f, 0.f, 0.f};

        // 2-ahead gather pipeline, static GA/GB roles (no runtime-indexed regs)
        {
            OffV o0 = loadOffs(0);
            GathV g0 = issueGather(0, o0);
            combineWrite(0, g0);
        }
        GathV GA = issueGather(1, loadOffs(1));   // for kc=1
        GathV GB = issueGather(2, loadOffs(2));   // for kc=2
        half8 bvC = *reinterpret_cast<const half8*>(bPtr);
        __syncthreads();

        auto bodyKC = [&](int kc, GathV& Gcur) {
            const short* AsC = &AsBuf[kc & 1][0];

            half8 bvN;
            if (kc + 1 < 18)
                bvN = *reinterpret_cast<const half8*>(bPtr + ((size_t)(kc + 1) << 11));

            half8 af[4];
            #pragma unroll
            for (int mt = 0; mt < 4; ++mt) {
                const int px = wm * 64 + mt * 16 + col;
                af[mt] = *reinterpret_cast<const half8*>(
                    &AsC[(px * 4 + (quad ^ ((px >> 1) & 3))) * 8]);
            }

            if (kc + 1 < 18) combineWrite(kc + 1, Gcur);
            if (kc + 3 < 18) Gcur = issueGather(kc + 3, loadOffs(kc + 3));

            __builtin_amdgcn_s_setprio(1);
            #pragma unroll
            for (int mt = 0; mt < 4; ++mt)
                acc2[mt] = __builtin_amdgcn_mfma_f32_16x16x32_f16(
                    af[mt], bvC, acc2[mt], 0, 0, 0);
            __builtin_amdgcn_s_setprio(0);
            __syncthreads();
            bvC = bvN;
        };

        #pragma unroll 1
        for (int kc2 = 0; kc2 < 18; kc2 += 2) {
            bodyKC(kc2,     GA);
            bodyKC(kc2 + 1, GB);
        }

        const int o = wn * 16 + col;
        const float bo = bias[o];
        float* op = out + ((size_t)b * C_ + o) * HW_ + (size_t)h * W_ + w0;
        #pragma unroll
        for (int mt = 0; mt < 4; ++mt) {
            const int px = wm * 64 + mt * 16 + quad * 4;
            float4 st = make_float4(acc2[mt][0] + bo, acc2[mt][1] + bo,
                                    acc2[mt][2] + bo, acc2[mt][3] + bo);
            *(float4*)(op + px) = st;
        }
    }
}

extern "C" void kernel_launch(void* const* d_in, const int* in_sizes, int n_in,
                              void* d_out, int out_size, void* d_ws, size_t ws_size,
                              hipStream_t stream) {
    const float* ref    = (const float*)d_in[0];
    const float* nbr    = (const float*)d_in[1];
    const float* off_w  = (const float*)d_in[2];
    const float* off_b  = (const float*)d_in[3];
    const float* msk_w  = (const float*)d_in[4];
    const float* msk_b  = (const float*)d_in[5];
    const float* weight = (const float*)d_in[6];
    const float* bias   = (const float*)d_in[7];
    float* out = (float*)d_out;

    // ws carve: Bw bf16 | xp (+16KB pad) | Bw3 f16 | nbf f16
    const size_t sz_Bw  = (size_t)36 * 256 * 32 * 2;             // 589824
    const size_t sz_xp  = (size_t)B_ * 4 * XPH_ * XPH_ * 32 * 2
                          + 16384;                               // 34097152
    const size_t sz_Bw3 = (size_t)18 * 64 * 32 * 2;              // 73728

    char* ws = (char*)d_ws;
    short* Bw  = (short*)ws;
    short* xp  = (short*)(ws + sz_Bw);
    short* Bw3 = (short*)(ws + sz_Bw + sz_xp);
    short* nbf = (short*)(ws + sz_Bw + sz_xp + sz_Bw3);

    prep_all<<<1812, 256, 0, stream>>>(ref, nbr, off_w, msk_w, weight,
                                       xp, nbf, Bw, Bw3);
    fused_conv_apply<<<1024, 512, 0, stream>>>(xp, Bw, off_b, msk_b,
                                               nbf, Bw3, bias, out);
}